// Round 9
// baseline (21339.035 us; speedup 1.0000x reference)
//
#include <hip/hip_runtime.h>

constexpr int NB = 32;    // batch
constexpr int NT = 128;   // time
constexpr int NE = 256;   // embed
constexpr int NH = 256;   // hidden
constexpr int NC = 16;    // classes

typedef _Float16 f16;
typedef f16 f16x2 __attribute__((ext_vector_type(2)));
typedef f16 f16x4 __attribute__((ext_vector_type(4)));
typedef f16 f16x8 __attribute__((ext_vector_type(8)));

__device__ __forceinline__ float sigmoidf_(float x) {
    return 1.f / (1.f + __expf(-x));
}
__device__ __forceinline__ float tanhf_(float x) {
    x = fminf(fmaxf(x, -15.f), 15.f);
    float e = __expf(-2.f * x);
    return (1.f - e) / (1.f + e);
}
__device__ __forceinline__ float dot4_(float4 a, float4 b) {
    return a.x * b.x + a.y * b.y + a.z * b.z + a.w * b.w;
}
#if __has_builtin(__builtin_amdgcn_fdot2)
__device__ __forceinline__ float fdot2_(f16x2 a, f16x2 b, float c) {
    return __builtin_amdgcn_fdot2(a, b, c, false);
}
#else
__device__ __forceinline__ float fdot2_(f16x2 a, f16x2 b, float c) {
    return (float)a[0] * (float)b[0] + (float)a[1] * (float)b[1] + c;
}
#endif
#define PAIR(v, k) __builtin_shufflevector((v), (v), (k), (k) + 1)

// dot of one 32-k piece (4 f16x8 chunks) against the thread's hv slice
__device__ __forceinline__ float dotp_(const f16x8* w, const f16x8* hv, float acc) {
#pragma unroll
    for (int cc = 0; cc < 4; ++cc) {
        acc = fdot2_(PAIR(w[cc], 0), PAIR(hv[cc], 0), acc);
        acc = fdot2_(PAIR(w[cc], 2), PAIR(hv[cc], 2), acc);
        acc = fdot2_(PAIR(w[cc], 4), PAIR(hv[cc], 4), acc);
        acc = fdot2_(PAIR(w[cc], 6), PAIR(hv[cc], 6), acc);
    }
    return acc;
}

// ---------------- Prologue 1: xp[t][b][j] = x[b][t][:] . W_in[j][:] + b_in[j]
__global__ __launch_bounds__(256) void k_lin_in(
    const float* __restrict__ x, const float* __restrict__ W_in,
    const float* __restrict__ b_in, float* __restrict__ xp) {
    const int tb = blockIdx.x;           // t*NB + b
    const int t = tb >> 5, b = tb & 31;
    const int tid = threadIdx.x;
    __shared__ __align__(16) float xl[NE];
    xl[tid] = x[(b * NT + t) * NE + tid];
    __syncthreads();
    const float* __restrict__ wr = W_in + tid * NE;
    float acc = b_in[tid];
#pragma unroll 8
    for (int k = 0; k < NE; k += 4)
        acc += dot4_(*(const float4*)(wr + k), *(const float4*)(xl + k));
    xp[tb * NH + tid] = acc;
}

// ---------------- Prologue 2: xw = xp.Wih^T + bih (+ bhh fold for r,z) ;
//                  uax = xp.Ua^T + ub
// ROUND 9: bhr/bhz are constant row-shifts inside sigmoid -> folded here so
// k_chain/k_attn don't carry them in registers. bhn is NOT foldable (it's
// multiplied by r), both consumers keep it.
__global__ __launch_bounds__(256) void k_proj(
    const float* __restrict__ xp, const float* __restrict__ Wih,
    const float* __restrict__ bih, const float* __restrict__ Ua,
    const float* __restrict__ ub, const float* __restrict__ bhh,
    float* __restrict__ xw, float* __restrict__ uax) {
    const int tb = blockIdx.x;
    const int tid = threadIdx.x;
    __shared__ __align__(16) float xl[NH];
    xl[tid] = xp[tb * NH + tid];
    __syncthreads();
    const float* __restrict__ wr = Wih + tid * NH;
    const float* __restrict__ wz = Wih + (NH + tid) * NH;
    const float* __restrict__ wn = Wih + (2 * NH + tid) * NH;
    const float* __restrict__ wu = Ua + tid * NH;
    float ar = bih[tid], az = bih[NH + tid], an = bih[2 * NH + tid], au = ub[tid];
#pragma unroll 4
    for (int k = 0; k < NH; k += 4) {
        float4 xv = *(const float4*)(xl + k);
        ar += dot4_(*(const float4*)(wr + k), xv);
        az += dot4_(*(const float4*)(wz + k), xv);
        an += dot4_(*(const float4*)(wn + k), xv);
        au += dot4_(*(const float4*)(wu + k), xv);
    }
    float* xwp = xw + tb * (3 * NH);
    xwp[tid] = ar + bhh[tid];              // bhr folded
    xwp[NH + tid] = az + bhh[NH + tid];    // bhz folded
    xwp[2 * NH + tid] = an;                // bhn NOT folded
    uax[tb * NH + tid] = au;
}

// ---------------- Pack: Wpk [kc][row] (k_attn), Wak (k_attn),
// Wpk2 (k_chain round-9 layout): chunk idx = q*3072 + p*256 + g*4 + cc
//   q = k-slice (8), p = gate*4+rr (12), g = row-group (64), cc = chunk (4)
//   element e: Whh[(p>>2)*256 + 4g + (p&3)][32q + 8cc + e]
__global__ __launch_bounds__(256) void k_pack(
    const float* __restrict__ Whh, const float* __restrict__ Wa,
    f16x8* __restrict__ Wpk, f16x8* __restrict__ Wak,
    f16x8* __restrict__ Wpk2) {
    const int id = blockIdx.x * 256 + threadIdx.x;
    if (id < 24576) {
        const int kc = id / 768, row = id % 768;
        const float* src = Whh + row * NH + kc * 8;
        f16x8 v;
#pragma unroll
        for (int m = 0; m < 8; ++m) v[m] = (f16)src[m];
        Wpk[id] = v;
    } else if (id < 32768) {
        const int id2 = id - 24576;      // < 8192
        const int kc = id2 >> 8, row = id2 & 255;
        const float* src = Wa + row * NH + kc * 8;
        f16x8 v;
#pragma unroll
        for (int m = 0; m < 8; ++m) v[m] = (f16)src[m];
        Wak[id2] = v;
    } else {
        const int id3 = id - 32768;      // < 24576
        const int cc = id3 & 3;
        const int g = (id3 >> 2) & 63;
        const int rem = id3 >> 8;        // q*12 + p
        const int p = rem % 12;
        const int q = rem / 12;
        const int row = (p >> 2) * 256 + 4 * g + (p & 3);
        const int kb = 32 * q + 8 * cc;
        const float* src = Whh + row * NH + kb;
        f16x8 v;
#pragma unroll
        for (int m = 0; m < 8; ++m) v[m] = (f16)src[m];
        Wpk2[id3] = v;
    }
}

// ---------------- Phase 1: sequential carried-hidden chain. 1 WG / batch.
// LEDGER r1-r8: step time ~2700-3000 cyc across spill (r2), conflicted-LDS
// (r7) and clean-LDS (r8) configs. The common binding constraint is LDS
// ISSUE THROUGHPUT (~12 cyc per ds_read_b128 wave-instr, m134): r8 had 35
// reads/thread x 8 waves x 12 = 3360 cyc (measured 2990). The 16 redundant
// hv reads/thread dominated.
// ROUND 9 mapping: g = tid>>3 owns rows {4g..4g+3} x 3 gates; q = tid&7 owns
// k-slice [32q, 32q+32). hv reads/thread: 16 -> 4. Weight sourcing:
//   regs: pieces p=0,1 (r rows 0,1)            32 VGPRs
//   LDS : pieces p=2,3 via sW[slot][tid]       8 ds_read, conflict-free
//   L2  : pieces p=4..11 rolling 2-piece window, batched issue (r8-proven)
// LDS instr/thread = 12 -> ~1150 cyc; VALU ~1540 (now binding); L2 ~585.
// h buffer: slice s at half-offset 40s (80B stride; start banks 20s%32 all
// distinct -> conflict-free reads AND writes).
__global__ __launch_bounds__(512) void k_chain(
    const f16x8* __restrict__ Wpk2, const float* __restrict__ bhh,
    const float* __restrict__ xw, float* __restrict__ Hc) {
    const int b = blockIdx.x;
    const int tid = threadIdx.x;
    const int g = tid >> 3;      // row group
    const int q = tid & 7;       // k-slice

    const f16x8* __restrict__ Wt = Wpk2 + q * 3072 + g * 4;

    __shared__ __align__(16) f16x8 sW[8 * 512];   // 64 KB, [slotchunk][tid]
    __shared__ __align__(16) f16 hb[2][320];      // 8 slices x 40-half stride

    // stage LDS pieces p=2,3
#pragma unroll
    for (int sc = 0; sc < 8; ++sc)
        sW[sc * 512 + tid] = Wt[(2 + (sc >> 2)) * 256 + (sc & 3)];

    // resident pieces p=0,1 (r-gate rows 4g, 4g+1)
    f16x8 rw0[4], rw1[4];
#pragma unroll
    for (int cc = 0; cc < 4; ++cc) { rw0[cc] = Wt[cc]; rw1[cc] = Wt[256 + cc]; }

    const float4 bn4 = *(const float4*)(bhh + 2 * NH + 4 * g);
    if (tid < 320) hb[0][tid] = (f16)0.f;
    float hp0 = 0.f, hp1 = 0.f, hp2 = 0.f, hp3 = 0.f;
    int cur = 0;
    __syncthreads();

#pragma unroll 1
    for (int i = 0; i < NT; ++i) {
#pragma unroll 1
        for (int t = 0; t <= i; ++t) {
            // L2 batch 1: pieces 4,5 (z rows 0,1)
            f16x8 wa[4], wb_[4];
#pragma unroll
            for (int cc = 0; cc < 4; ++cc) {
                wa[cc] = Wt[4 * 256 + cc];
                wb_[cc] = Wt[5 * 256 + cc];
            }
            const float* __restrict__ xq = xw + (size_t)(t * NB + b) * (3 * NH);
            const float4 xr4 = *(const float4*)(xq + 4 * g);
            const float4 xz4 = *(const float4*)(xq + NH + 4 * g);
            const float4 xn4 = *(const float4*)(xq + 2 * NH + 4 * g);

            const f16* hc = hb[cur] + 40 * q;
            f16x8 hvv[4];
#pragma unroll
            for (int m = 0; m < 4; ++m) hvv[m] = *(const f16x8*)(hc + 8 * m);

            // r gate: resident + LDS pieces
            float ar0 = dotp_(rw0, hvv, 0.f);
            float ar1 = dotp_(rw1, hvv, 0.f);
            f16x8 lw[4];
#pragma unroll
            for (int cc = 0; cc < 4; ++cc) lw[cc] = sW[cc * 512 + tid];
            float ar2 = dotp_(lw, hvv, 0.f);
#pragma unroll
            for (int cc = 0; cc < 4; ++cc) lw[cc] = sW[(4 + cc) * 512 + tid];
            float ar3 = dotp_(lw, hvv, 0.f);

            // L2 batch 2 (pieces 6,7); compute batch 1
            f16x8 wc[4], wd[4];
#pragma unroll
            for (int cc = 0; cc < 4; ++cc) {
                wc[cc] = Wt[6 * 256 + cc];
                wd[cc] = Wt[7 * 256 + cc];
            }
            float az0 = dotp_(wa, hvv, 0.f);
            float az1 = dotp_(wb_, hvv, 0.f);

            // L2 batch 3 (pieces 8,9); compute batch 2
#pragma unroll
            for (int cc = 0; cc < 4; ++cc) {
                wa[cc] = Wt[8 * 256 + cc];
                wb_[cc] = Wt[9 * 256 + cc];
            }
            float az2 = dotp_(wc, hvv, 0.f);
            float az3 = dotp_(wd, hvv, 0.f);

            // L2 batch 4 (pieces 10,11); compute batch 3
#pragma unroll
            for (int cc = 0; cc < 4; ++cc) {
                wc[cc] = Wt[10 * 256 + cc];
                wd[cc] = Wt[11 * 256 + cc];
            }
            float an0 = dotp_(wa, hvv, 0.f);
            float an1 = dotp_(wb_, hvv, 0.f);
            float an2 = dotp_(wc, hvv, 0.f);
            float an3 = dotp_(wd, hvv, 0.f);

            // 3-level xor reduce over the 8 k-slices (lanes q, clusters of 8)
            ar0 += __shfl_xor(ar0, 1); ar0 += __shfl_xor(ar0, 2); ar0 += __shfl_xor(ar0, 4);
            ar1 += __shfl_xor(ar1, 1); ar1 += __shfl_xor(ar1, 2); ar1 += __shfl_xor(ar1, 4);
            ar2 += __shfl_xor(ar2, 1); ar2 += __shfl_xor(ar2, 2); ar2 += __shfl_xor(ar2, 4);
            ar3 += __shfl_xor(ar3, 1); ar3 += __shfl_xor(ar3, 2); ar3 += __shfl_xor(ar3, 4);
            az0 += __shfl_xor(az0, 1); az0 += __shfl_xor(az0, 2); az0 += __shfl_xor(az0, 4);
            az1 += __shfl_xor(az1, 1); az1 += __shfl_xor(az1, 2); az1 += __shfl_xor(az1, 4);
            az2 += __shfl_xor(az2, 1); az2 += __shfl_xor(az2, 2); az2 += __shfl_xor(az2, 4);
            az3 += __shfl_xor(az3, 1); az3 += __shfl_xor(az3, 2); az3 += __shfl_xor(az3, 4);
            an0 += __shfl_xor(an0, 1); an0 += __shfl_xor(an0, 2); an0 += __shfl_xor(an0, 4);
            an1 += __shfl_xor(an1, 1); an1 += __shfl_xor(an1, 2); an1 += __shfl_xor(an1, 4);
            an2 += __shfl_xor(an2, 1); an2 += __shfl_xor(an2, 2); an2 += __shfl_xor(an2, 4);
            an3 += __shfl_xor(an3, 1); an3 += __shfl_xor(an3, 2); an3 += __shfl_xor(an3, 4);

            // gates (bhr/bhz folded into xw by k_proj; bhn explicit)
            const float r0 = sigmoidf_(xr4.x + ar0);
            const float r1 = sigmoidf_(xr4.y + ar1);
            const float r2 = sigmoidf_(xr4.z + ar2);
            const float r3 = sigmoidf_(xr4.w + ar3);
            const float z0 = sigmoidf_(xz4.x + az0);
            const float z1 = sigmoidf_(xz4.y + az1);
            const float z2 = sigmoidf_(xz4.z + az2);
            const float z3 = sigmoidf_(xz4.w + az3);
            const float n0 = tanhf_(xn4.x + r0 * (an0 + bn4.x));
            const float n1 = tanhf_(xn4.y + r1 * (an1 + bn4.y));
            const float n2 = tanhf_(xn4.z + r2 * (an2 + bn4.z));
            const float n3 = tanhf_(xn4.w + r3 * (an3 + bn4.w));
            const float h0 = (1.f - z0) * n0 + z0 * hp0; hp0 = h0;
            const float h1 = (1.f - z1) * n1 + z1 * hp1; hp1 = h1;
            const float h2 = (1.f - z2) * n2 + z2 * hp2; hp2 = h2;
            const float h3 = (1.f - z3) * n3 + z3 * hp3; hp3 = h3;

            if (q == 0) {
                f16x4 hv4;
                hv4[0] = (f16)h0; hv4[1] = (f16)h1;
                hv4[2] = (f16)h2; hv4[3] = (f16)h3;
                // rows 4g..4g+3: slice g>>3, offset 4*(g&7) halves
                *(f16x4*)(hb[cur ^ 1] + 40 * (g >> 3) + 4 * (g & 7)) = hv4;
                if (t == i) {
                    float4 o; o.x = h0; o.y = h1; o.z = h2; o.w = h3;
                    *(float4*)(Hc + ((size_t)i * NB + b) * NH + 4 * g) = o;
                }
            }
            cur ^= 1;
            __syncthreads();
        }
    }
}

// ---------------- Phase 2: lockstep re-run of all prefix chains + fused attention.
// Grid: 32 b x 8 bk; each WG owns 16 chains i = bk + 8u, 512 threads:
// col = tid>>1 (0..255), c = tid&1 (128-wide k-half). 8 waves = 2 waves/SIMD.
// ROUND 9: bhr/bhz now folded into xw by k_proj (removed here); bhn kept.
__global__ __attribute__((amdgpu_waves_per_eu(2, 2))) __launch_bounds__(512)
void k_attn(
    const float* __restrict__ Hc, const float* __restrict__ xw,
    const float* __restrict__ uax, const float* __restrict__ xp,
    const f16x8* __restrict__ Wpk, const f16x8* __restrict__ Wak,
    const float* __restrict__ bhh, const float* __restrict__ ba,
    const float* __restrict__ va_w, const float* __restrict__ Wo,
    const float* __restrict__ bo, float* __restrict__ out) {
    const int b  = blockIdx.x >> 3;
    const int bk = blockIdx.x & 7;
    const int tid = threadIdx.x;
    const int col = tid >> 1, c = tid & 1;
    const int lane = tid & 63, wid = tid >> 6;

    __shared__ __align__(16) float S[16][NH];
    __shared__ __align__(16) f16 Sh[16][NH];
    __shared__ float red1[8][16];
    __shared__ float mL[16], lL[16], aL[16], eL[16];
    __shared__ float redH[8][256];

    const float bhn = bhh[2 * NH + col];
    const float ba_j = ba[col], va_j = va_w[col];
    float ctx[16];
#pragma unroll
    for (int u = 0; u < 16; ++u) {
        const int ic = bk + 8 * u;
        const float hv = (ic == 0) ? 0.f : Hc[((size_t)(ic - 1) * NB + b) * NH + col];
        if (c == 0) { S[u][col] = hv; Sh[u][col] = (f16)hv; }
        ctx[u] = 0.f;
    }
    if (tid < 16) { mL[tid] = -1e30f; lL[tid] = 0.f; }
    __syncthreads();

    const int imax = bk + 8 * 15;
#pragma unroll 1
    for (int t = 0; t <= imax; ++t) {
        const size_t base = (size_t)(t * NB + b);
        const float xr = xw[base * 3 * NH + col];
        const float xz = xw[base * 3 * NH + NH + col];
        const float xn = xw[base * 3 * NH + 2 * NH + col];
        const float ux = uax[base * NH + col];
        const float xpt = xp[base * NH + col];

        // ---- GRU matvec for active chains (i >= t); k-half per c
        float ar[16], az[16], an[16];
#pragma unroll
        for (int u = 0; u < 16; ++u) { ar[u] = 0.f; az[u] = 0.f; an[u] = 0.f; }
#pragma unroll 2
        for (int kk = 0; kk < 16; ++kk) {
            const int kc = kk * 2 + c;
            const f16x8 wR = Wpk[kc * 768 + col];
            const f16x8 wZ = Wpk[kc * 768 + 256 + col];
            const f16x8 wN = Wpk[kc * 768 + 512 + col];
#pragma unroll
            for (int u = 0; u < 16; ++u) {
                if (bk + 8 * u < t) continue;      // frozen chain (uniform branch)
                const f16x8 hv = *(const f16x8*)&Sh[u][kc * 8];
                const f16x2 h0 = PAIR(hv, 0), h1 = PAIR(hv, 2),
                            h2 = PAIR(hv, 4), h3 = PAIR(hv, 6);
                ar[u] = fdot2_(PAIR(wR, 0), h0, ar[u]);
                ar[u] = fdot2_(PAIR(wR, 2), h1, ar[u]);
                ar[u] = fdot2_(PAIR(wR, 4), h2, ar[u]);
                ar[u] = fdot2_(PAIR(wR, 6), h3, ar[u]);
                az[u] = fdot2_(PAIR(wZ, 0), h0, az[u]);
                az[u] = fdot2_(PAIR(wZ, 2), h1, az[u]);
                az[u] = fdot2_(PAIR(wZ, 4), h2, az[u]);
                az[u] = fdot2_(PAIR(wZ, 6), h3, az[u]);
                an[u] = fdot2_(PAIR(wN, 0), h0, an[u]);
                an[u] = fdot2_(PAIR(wN, 2), h1, an[u]);
                an[u] = fdot2_(PAIR(wN, 4), h2, an[u]);
                an[u] = fdot2_(PAIR(wN, 6), h3, an[u]);
            }
        }
        float hn[16];
#pragma unroll
        for (int u = 0; u < 16; ++u) {
            if (bk + 8 * u < t) continue;
            float arf = ar[u] + __shfl_xor(ar[u], 1);
            float azf = az[u] + __shfl_xor(az[u], 1);
            float anf = an[u] + __shfl_xor(an[u], 1);
            const float r = sigmoidf_(xr + arf);
            const float z = sigmoidf_(xz + azf);
            const float n = tanhf_(xn + r * (anf + bhn));
            hn[u] = (1.f - z) * n + z * S[u][col];
        }
        __syncthreads();                      // all Sh reads of this step done
#pragma unroll
        for (int u = 0; u < 16; ++u) {
            if (bk + 8 * u < t) continue;
            if (c == 0) { S[u][col] = hn[u]; Sh[u][col] = (f16)hn[u]; }
        }
        __syncthreads();                      // Sh now holds outs[t]

        // ---- attention scores for active chains
        float sc[16];
#pragma unroll
        for (int u = 0; u < 16; ++u) sc[u] = 0.f;
#pragma unroll 2
        for (int kk = 0; kk < 16; ++kk) {
            const int kc = kk * 2 + c;
            const f16x8 wA = Wak[kc * 256 + col];
#pragma unroll
            for (int u = 0; u < 16; ++u) {
                if (bk + 8 * u < t) continue;
                const f16x8 hv = *(const f16x8*)&Sh[u][kc * 8];
                sc[u] = fdot2_(PAIR(wA, 0), PAIR(hv, 0), sc[u]);
                sc[u] = fdot2_(PAIR(wA, 2), PAIR(hv, 2), sc[u]);
                sc[u] = fdot2_(PAIR(wA, 4), PAIR(hv, 4), sc[u]);
                sc[u] = fdot2_(PAIR(wA, 6), PAIR(hv, 6), sc[u]);
            }
        }
#pragma unroll
        for (int u = 0; u < 16; ++u) {
            if (bk + 8 * u < t) continue;
            const float sv = sc[u] + __shfl_xor(sc[u], 1);   // full-k (Wa h)[col]
            float p = (c == 0) ? va_j * tanhf_(sv + ba_j + ux) : 0.f;
#pragma unroll
            for (int off = 32; off; off >>= 1) p += __shfl_xor(p, off);
            if (lane == 0) red1[wid][u] = p;
        }
        __syncthreads();
        if (tid < 16 && bk + 8 * tid >= t) {   // online softmax state per chain
            float s = 0.f;
#pragma unroll
            for (int w = 0; w < 8; ++w) s += red1[w][tid];
            const float mo = mL[tid];
            const float mn = fmaxf(mo, s);
            const float e  = __expf(s - mn);
            const float al = __expf(mo - mn);
            lL[tid] = lL[tid] * al + e;
            mL[tid] = mn; aL[tid] = al; eL[tid] = e;
        }
        __syncthreads();
#pragma unroll
        for (int u = 0; u < 16; ++u) {
            if (bk + 8 * u < t) continue;
            ctx[u] = ctx[u] * aL[u] + eL[u] * xpt;
        }
    }

    // ---- output head per chain: logits = [h_last, context] @ Wo^T + bo
#pragma unroll 1
    for (int u = 0; u < 16; ++u) {
        const float hl = S[u][col];           // final state == h_last(i)
        const float cx = ctx[u] / lL[u];
#pragma unroll
        for (int cls = 0; cls < NC; ++cls) {
            float p = Wo[cls * (2 * NH) + col] * hl + Wo[cls * (2 * NH) + NH + col] * cx;
            p = (c == 0) ? p : 0.f;
#pragma unroll
            for (int off = 32; off; off >>= 1) p += __shfl_xor(p, off);
            if (lane == 0) redH[wid][u * 16 + cls] = p;
        }
    }
    __syncthreads();
    if (tid < 256) {
        const int u = tid >> 4, cls = tid & 15;
        const int ic = bk + 8 * u;
        float lg = bo[cls];
#pragma unroll
        for (int w = 0; w < 8; ++w) lg += redH[w][tid];
        out[((size_t)b * NT + ic) * NC + cls] = sigmoidf_(lg);
    }
}

extern "C" void kernel_launch(void* const* d_in, const int* in_sizes, int n_in,
                              void* d_out, int out_size, void* d_ws, size_t ws_size,
                              hipStream_t stream) {
    (void)in_sizes; (void)n_in; (void)out_size; (void)ws_size;
    const float* x    = (const float*)d_in[0];
    const float* W_in = (const float*)d_in[1];
    const float* b_in = (const float*)d_in[2];
    const float* Wih  = (const float*)d_in[3];
    const float* bih  = (const float*)d_in[4];
    const float* Whh  = (const float*)d_in[5];
    const float* bhh  = (const float*)d_in[6];
    const float* Wa   = (const float*)d_in[7];
    const float* ba   = (const float*)d_in[8];
    const float* Ua   = (const float*)d_in[9];
    const float* ub   = (const float*)d_in[10];
    const float* va_w = (const float*)d_in[11];
    // d_in[12] = va_b: cancels in softmax
    const float* Wo   = (const float*)d_in[13];
    const float* bo   = (const float*)d_in[14];
    float* out = (float*)d_out;

    float* ws  = (float*)d_ws;
    float* xp  = ws;                                    // NT*NB*NH        (4 MB)
    float* xw  = xp  + (size_t)NT * NB * NH;            // NT*NB*3NH       (12.6 MB)
    float* uax = xw  + (size_t)NT * NB * 3 * NH;        // NT*NB*NH        (4 MB)
    float* Hc  = uax + (size_t)NT * NB * NH;            // NT*NB*NH        (4 MB)
    f16x8* Wpk = (f16x8*)(Hc + (size_t)NT * NB * NH);   // 24576 f16x8     (384 KB)
    f16x8* Wak = Wpk + 24576;                           // 8192 f16x8      (128 KB)
    f16x8* Wpk2 = Wak + 8192;                           // 24576 f16x8     (384 KB)

    hipLaunchKernelGGL(k_lin_in, dim3(NT * NB), dim3(256), 0, stream, x, W_in, b_in, xp);
    hipLaunchKernelGGL(k_proj,   dim3(NT * NB), dim3(256), 0, stream, xp, Wih, bih, Ua, ub, bhh, xw, uax);
    hipLaunchKernelGGL(k_pack,   dim3(224),     dim3(256), 0, stream, Whh, Wa, Wpk, Wak, Wpk2);
    hipLaunchKernelGGL(k_chain,  dim3(NB),      dim3(512), 0, stream, Wpk2, bhh, xw, Hc);
    hipLaunchKernelGGL(k_attn,   dim3(NB * 8),  dim3(512), 0, stream,
                       Hc, xw, uax, xp, Wpk, Wak, bhh, ba, va_w, Wo, bo, out);
}